// Round 15
// baseline (512.645 us; speedup 1.0000x reference)
//
#include <hip/hip_runtime.h>
#include <math.h>

#define T_STEPS 19
#define V 50257
#define EMB 300
#define HDIM 512
#define NP 256
#define ML 50
#define CIN 812
#define NEGV -1e9f
#define NBLK 64

// ---- workspace layout (float indices) ----
#define OFF_X      0                         // 19*300
#define OFF_POP    5700                      // 19*256
#define OFF_PL     10564                     // 19*256
#define OFF_PC     15428                     // 19*512
#define OFF_HS     25156                     // 20*512
#define OFF_H1OP   35396                     // 256
#define OFF_H1L    35652                     // 256
#define OFF_C1     35908                     // 512
#define OFF_G      36420                     // 512
#define OFF_LOGOP  36932                     // 256
#define OFF_LOGL   37188                     // 64
#define OFF_MPROP  37252                     // 512*256 = 131072
#define OFF_MENC   168324                    // 512*50  = 25600
#define OFF_BAR    193924                    // flags @ +16 + 16*b (64B stride — proven R9)

// ---- output layout (floats) ----
#define OUT_LOGITS 0
#define OUT_ATTW   ((long)T_STEPS * V)
#define OUT_ATTOB  (OUT_ATTW + (long)T_STEPS * ML)

__device__ __forceinline__ float wred(float v) {
  v += __shfl_xor(v, 32, 64);
  v += __shfl_xor(v, 16, 64);
  v += __shfl_xor(v, 8, 64);
  v += __shfl_xor(v, 4, 64);
  v += __shfl_xor(v, 2, 64);
  v += __shfl_xor(v, 1, 64);
  return v;
}

__device__ __forceinline__ float dot4(float4 a, float4 b) {
  return a.x * b.x + a.y * b.y + a.z * b.z + a.w * b.w;
}

// ---- agent-coherent access (bypass non-coherent L1/L2; hit the MALL) ----
__device__ __forceinline__ void gstore(float* p, float v) {
  __hip_atomic_store(p, v, __ATOMIC_RELAXED, __HIP_MEMORY_SCOPE_AGENT);
}
__device__ __forceinline__ float ld1c(const float* p) {
  return __hip_atomic_load(p, __ATOMIC_RELAXED, __HIP_MEMORY_SCOPE_AGENT);
}
__device__ __forceinline__ float2 ld2c(const float* p) {
  unsigned long long u = __hip_atomic_load((const unsigned long long*)p,
                                           __ATOMIC_RELAXED, __HIP_MEMORY_SCOPE_AGENT);
  float2 r;
  r.x = __uint_as_float((unsigned)u);
  r.y = __uint_as_float((unsigned)(u >> 32));
  return r;
}
__device__ __forceinline__ float4 ld4c(const float* p) {
  float2 a = ld2c(p), b = ld2c(p + 2);
  return make_float4(a.x, a.y, b.x, b.y);
}

// All-poll-all fence-free grid barrier (proven R9/R12, 64B-stride flags):
// each block stores its flag; every block's wave-0 lanes poll all 64 flags.
__device__ __forceinline__ void gbar(float* wsb, unsigned bar) {
  asm volatile("s_waitcnt vmcnt(0)" ::: "memory");
  __syncthreads();
  unsigned* flags = (unsigned*)(wsb + OFF_BAR) + 16;
  if (threadIdx.x == 0) {
    __hip_atomic_store(flags + 16 * blockIdx.x, bar, __ATOMIC_RELAXED, __HIP_MEMORY_SCOPE_AGENT);
  }
  asm volatile("" ::: "memory");
  if (threadIdx.x < 64) {
    unsigned* f = flags + 16 * threadIdx.x;
    while (__hip_atomic_load(f, __ATOMIC_RELAXED, __HIP_MEMORY_SCOPE_AGENT) < bar) {
      __builtin_amdgcn_s_sleep(1);
    }
  }
  __syncthreads();
}

// Precompute X = relu(emb[token]) for all steps; copy Hs[0].
__global__ void k_pre1(const int* __restrict__ tok0, const int* __restrict__ ans,
                       const float* __restrict__ emb, const float* __restrict__ hidden,
                       float* __restrict__ ws) {
  int tid = blockIdx.x * 256 + threadIdx.x;
  if (tid < T_STEPS * EMB) {
    int s = tid / EMB, j = tid - s * EMB;
    int t = (s == 0) ? tok0[0] : ans[s];
    float v = emb[(long)t * EMB + j];
    ws[OFF_X + tid] = v > 0.f ? v : 0.f;
  } else {
    int k = tid - T_STEPS * EMB;
    if (k < HDIM) ws[OFF_HS + k] = hidden[k];
  }
}

// P_op/P_l/P_c: x-column partials + layer-1 biases. wave-per-row, 19*1024 rows.
__global__ void k_pre2(const float* __restrict__ w1op, const float* __restrict__ b1op,
                       const float* __restrict__ w1l,  const float* __restrict__ b1l,
                       const float* __restrict__ wc1,  const float* __restrict__ bc1,
                       float* __restrict__ ws) {
  int gw = (blockIdx.x * 256 + threadIdx.x) >> 6;
  int lane = threadIdx.x & 63;
  int s = gw >> 10;
  int rr = gw & 1023;
  if (s >= T_STEPS) return;
  const float* wrow; const float* bias; float* dst; int r;
  if (rr < 256)      { r = rr;       wrow = w1op + (long)r * CIN; bias = b1op; dst = ws + OFF_POP + s * 256 + r; }
  else if (rr < 512) { r = rr - 256; wrow = w1l  + (long)r * CIN; bias = b1l;  dst = ws + OFF_PL  + s * 256 + r; }
  else               { r = rr - 512; wrow = wc1  + (long)r * CIN; bias = bc1;  dst = ws + OFF_PC  + s * 512 + r; }
  const float* x = ws + OFF_X + s * EMB;
  float acc = 0.f;
#pragma unroll
  for (int it = 0; it < 5; ++it) {
    int j = it * 64 + lane;
    if (j < EMB) acc += wrow[j] * x[j];
  }
  acc = wred(acc);
  if (lane == 0) *dst = acc + bias[r];
}

// M_prop[r][p] = sum_k cmb_w1[r][556+k]*prop[p][k]; M_enc[r][j] = sum_k cmb_w1[r][300+k]*enc[j][k]
#define LDSF 12850
__global__ void __launch_bounds__(256) k_mprep(const float* __restrict__ cw1,
                                               const float* __restrict__ prop,
                                               const float* __restrict__ enc,
                                               float* __restrict__ ws) {
  __shared__ float lds[LDSF];
  int tid = threadIdx.x, r = blockIdx.x;
  float acc = 0.f;
  for (int kc = 0; kc < 8; ++kc) {
    __syncthreads();
#pragma unroll
    for (int i = 0; i < 8; ++i) {
      int f = tid + 256 * i; int row = f >> 3, q = f & 7;
      float4 v = *(const float4*)(prop + (long)row * 256 + kc * 32 + 4 * q);
      float* p = lds + row * 33 + 4 * q;
      p[0] = v.x; p[1] = v.y; p[2] = v.z; p[3] = v.w;
    }
    __syncthreads();
    const float* wbase = cw1 + (long)r * CIN + 556 + kc * 32;
    const float* pl = lds + tid * 33;
#pragma unroll
    for (int k4 = 0; k4 < 8; ++k4) {
      float4 w4 = *(const float4*)(wbase + 4 * k4);
      const float* pp = pl + 4 * k4;
      acc += w4.x * pp[0] + w4.y * pp[1] + w4.z * pp[2] + w4.w * pp[3];
    }
  }
  ws[OFF_MPROP + (long)r * 256 + tid] = acc;
  __syncthreads();
  for (int i = 0; i < 13; ++i) {
    int f = tid + 256 * i;
    if (f < 3200) {
      int row = f >> 6, q = f & 63;
      float4 v = *(const float4*)(enc + (long)row * 256 + 4 * q);
      float* p = lds + row * 257 + 4 * q;
      p[0] = v.x; p[1] = v.y; p[2] = v.z; p[3] = v.w;
    }
  }
  __syncthreads();
  if (tid < ML) {
    const float* wb2 = cw1 + (long)r * CIN + 300;
    const float* el = lds + tid * 257;
    float a2 = 0.f;
#pragma unroll 8
    for (int k = 0; k < 256; ++k) a2 += wb2[k] * el[k];
    ws[OFF_MENC + (long)r * ML + tid] = a2;
  }
}

// Persistent fused recurrence (R9 verbatim): 5 hops/step, 64B-stride flag barrier,
// ALL step-invariant weights in registers. 64 blocks x 256 threads.
__global__ void __launch_bounds__(256, 1) k_recur(
    const float* __restrict__ w1op, const float* __restrict__ w1l,
    const float* __restrict__ whh,  const float* __restrict__ bhh,
    const float* __restrict__ w2op, const float* __restrict__ b2op,
    const float* __restrict__ w2l,  const float* __restrict__ b2l,
    const int* __restrict__ obj_mask, const int* __restrict__ lang_mask,
    const float* __restrict__ wc2,  const float* __restrict__ bc2,
    const float* __restrict__ wih,  const float* __restrict__ bih,
    float* ws, float* __restrict__ out) {
  const int tid = threadIdx.x;
  const int lane = tid & 63;
  const int wv = (blockIdx.x << 2) + (tid >> 6);   // 0..255
  const int r0 = 2 * wv, r1 = 2 * wv + 1;          // owned rows 0..511
  const int l4 = 4 * lane;
  unsigned bar = 1;
  __shared__ float red[256];
  __shared__ __align__(16) float sm_aop[256];
  __shared__ float sm_al[64];

  // ---- one-time register preload of step-invariant weight slices ----
  const float* wa0p = (r0 < 256) ? (w1op + (long)r0 * CIN + 300) : (w1l + (long)(r0 - 256) * CIN + 300);
  const float* wa1p = (r1 < 256) ? (w1op + (long)r1 * CIN + 300) : (w1l + (long)(r1 - 256) * CIN + 300);
  float4 WA00 = *(const float4*)(wa0p + l4), WA01 = *(const float4*)(wa0p + 256 + l4);
  float4 WA10 = *(const float4*)(wa1p + l4), WA11 = *(const float4*)(wa1p + 256 + l4);
  const float* q;
  q = whh + (long)r0 * HDIM;           float4 WH00 = *(const float4*)(q + l4), WH01 = *(const float4*)(q + 256 + l4);
  q = whh + (long)(r0 + 512) * HDIM;   float4 WH10 = *(const float4*)(q + l4), WH11 = *(const float4*)(q + 256 + l4);
  q = whh + (long)(r0 + 1024) * HDIM;  float4 WH20 = *(const float4*)(q + l4), WH21 = *(const float4*)(q + 256 + l4);
  q = whh + (long)r1 * HDIM;           float4 WH30 = *(const float4*)(q + l4), WH31 = *(const float4*)(q + 256 + l4);
  q = whh + (long)(r1 + 512) * HDIM;   float4 WH40 = *(const float4*)(q + l4), WH41 = *(const float4*)(q + 256 + l4);
  q = whh + (long)(r1 + 1024) * HDIM;  float4 WH50 = *(const float4*)(q + l4), WH51 = *(const float4*)(q + 256 + l4);
  float4 W2  = *(const float4*)(w2op + (long)wv * 256 + l4);
  float4 W2L = (wv < ML) ? *(const float4*)(w2l + (long)wv * 256 + l4) : make_float4(0.f, 0.f, 0.f, 0.f);
  float4 MP0 = *(const float4*)(ws + OFF_MPROP + (long)r0 * 256 + l4);
  float4 MP1 = *(const float4*)(ws + OFF_MPROP + (long)r1 * 256 + l4);
  float  ME0 = (lane < ML) ? ws[OFF_MENC + (long)r0 * ML + lane] : 0.f;
  float  ME1 = (lane < ML) ? ws[OFF_MENC + (long)r1 * ML + lane] : 0.f;
  q = wc2 + (long)r0 * HDIM;           float4 WC00 = *(const float4*)(q + l4), WC01 = *(const float4*)(q + 256 + l4);
  q = wc2 + (long)r1 * HDIM;           float4 WC10 = *(const float4*)(q + l4), WC11 = *(const float4*)(q + 256 + l4);
  q = wih + (long)r0 * HDIM;           float4 WI00 = *(const float4*)(q + l4), WI01 = *(const float4*)(q + 256 + l4);
  q = wih + (long)(r0 + 512) * HDIM;   float4 WI10 = *(const float4*)(q + l4), WI11 = *(const float4*)(q + 256 + l4);
  q = wih + (long)(r0 + 1024) * HDIM;  float4 WI20 = *(const float4*)(q + l4), WI21 = *(const float4*)(q + 256 + l4);
  q = wih + (long)r1 * HDIM;           float4 WI30 = *(const float4*)(q + l4), WI31 = *(const float4*)(q + 256 + l4);
  q = wih + (long)(r1 + 512) * HDIM;   float4 WI40 = *(const float4*)(q + l4), WI41 = *(const float4*)(q + 256 + l4);
  q = wih + (long)(r1 + 1024) * HDIM;  float4 WI50 = *(const float4*)(q + l4), WI51 = *(const float4*)(q + 256 + l4);
  float BH0 = bhh[r0], BH1 = bhh[512 + r0], BH2 = bhh[1024 + r0];
  float BH3 = bhh[r1], BH4 = bhh[512 + r1], BH5 = bhh[1024 + r1];
  float BI0 = bih[r0], BI1 = bih[512 + r0], BI2 = bih[1024 + r0];
  float BI3 = bih[r1], BI4 = bih[512 + r1], BI5 = bih[1024 + r1];
  float BC0 = bc2[r0], BC1 = bc2[r1];
  float B2  = b2op[wv];
  float B2Lv = (wv < ML) ? b2l[wv] : 0.f;

  for (int s = 0; s < T_STEPS; ++s) {
    float ghr0, ghz0, ghn0, ghr1, ghz1, ghn1;
    // ---------- Phase A: h1 rows {r0,r1}; gh -> regs ----------
    {
      const float* h = ws + OFF_HS + s * HDIM;
      float4 ha = ld4c(h + l4);
      float4 hb = ld4c(h + 256 + l4);
      float a0 = dot4(WA00, ha) + dot4(WA01, hb);
      float a1 = dot4(WA10, ha) + dot4(WA11, hb);
      float b0 = dot4(WH00, ha) + dot4(WH01, hb);
      float b1 = dot4(WH10, ha) + dot4(WH11, hb);
      float b2 = dot4(WH20, ha) + dot4(WH21, hb);
      float b3 = dot4(WH30, ha) + dot4(WH31, hb);
      float b4 = dot4(WH40, ha) + dot4(WH41, hb);
      float b5 = dot4(WH50, ha) + dot4(WH51, hb);
      a0 = wred(a0); a1 = wred(a1);
      b0 = wred(b0); b1 = wred(b1); b2 = wred(b2);
      b3 = wred(b3); b4 = wred(b4); b5 = wred(b5);
      ghr0 = b0 + BH0; ghz0 = b1 + BH1; ghn0 = b2 + BH2;
      ghr1 = b3 + BH3; ghz1 = b4 + BH4; ghn1 = b5 + BH5;
      if (lane == 0) {
        float v0 = a0 + ((r0 < 256) ? ws[OFF_POP + s * 256 + r0] : ws[OFF_PL + s * 256 + (r0 - 256)]);
        float v1 = a1 + ((r1 < 256) ? ws[OFF_POP + s * 256 + r1] : ws[OFF_PL + s * 256 + (r1 - 256)]);
        float* d0 = (r0 < 256) ? (ws + OFF_H1OP + r0) : (ws + OFF_H1L + (r0 - 256));
        float* d1 = (r1 < 256) ? (ws + OFF_H1OP + r1) : (ws + OFF_H1L + (r1 - 256));
        gstore(d0, v0 > 0.f ? v0 : 0.f);
        gstore(d1, v1 > 0.f ? v1 : 0.f);
      }
    }
    gbar(ws, bar++);
    // ---------- Phase B: attention logits ----------
    {
      float4 h1 = ld4c(ws + OFF_H1OP + l4);
      float acc = wred(dot4(W2, h1));
      if (lane == 0) gstore(ws + OFF_LOGOP + wv, acc + B2);
      if (wv < ML) {
        float4 h1l = ld4c(ws + OFF_H1L + l4);
        float accl = wred(dot4(W2L, h1l));
        if (lane == 0) gstore(ws + OFF_LOGL + wv, accl + B2Lv);
      }
    }
    gbar(ws, bar++);
    // ---------- Phase C: block-redundant softmax + c1 rows {r0,r1} ----------
    {
      float lv = ld1c(ws + OFF_LOGOP + tid);
      float vo = (obj_mask[tid] != 0) ? NEGV : lv;
      red[tid] = vo; __syncthreads();
      for (int st = 128; st > 0; st >>= 1) { if (tid < st) red[tid] = fmaxf(red[tid], red[tid + st]); __syncthreads(); }
      float mo = red[0]; __syncthreads();
      float eo = expf(vo - mo);
      red[tid] = eo; __syncthreads();
      for (int st = 128; st > 0; st >>= 1) { if (tid < st) red[tid] += red[tid + st]; __syncthreads(); }
      float aop = eo / red[0];
      sm_aop[tid] = aop;
      __syncthreads();
      float ll = 0.f;
      if (tid < ML) ll = ld1c(ws + OFF_LOGL + tid);
      float vl = (tid < ML) ? ((lang_mask[tid] != 0) ? NEGV : ll) : -3e38f;
      red[tid] = vl; __syncthreads();
      for (int st = 128; st > 0; st >>= 1) { if (tid < st) red[tid] = fmaxf(red[tid], red[tid + st]); __syncthreads(); }
      float ml_ = red[0]; __syncthreads();
      float el = (tid < ML) ? expf(vl - ml_) : 0.f;
      red[tid] = el; __syncthreads();
      for (int st = 128; st > 0; st >>= 1) { if (tid < st) red[tid] += red[tid + st]; __syncthreads(); }
      float al = el / red[0];
      if (tid < 64) sm_al[tid] = (tid < ML) ? al : 0.f;
      __syncthreads();
      if (blockIdx.x == 0) {
        out[OUT_ATTOB + (long)s * NP + tid] = aop;
        if (tid < ML) out[OUT_ATTW + (long)s * ML + tid] = al;
      }
      float4 a4 = *(const float4*)(&sm_aop[l4]);
      float acc0 = dot4(MP0, a4);
      float acc1 = dot4(MP1, a4);
      if (lane < ML) {
        float alv = sm_al[lane];
        acc0 += ME0 * alv;
        acc1 += ME1 * alv;
      }
      acc0 = wred(acc0); acc1 = wred(acc1);
      if (lane == 0) {
        float v0 = acc0 + ws[OFF_PC + s * HDIM + r0];
        float v1 = acc1 + ws[OFF_PC + s * HDIM + r1];
        gstore(ws + OFF_C1 + r0, v0 > 0.f ? v0 : 0.f);
        gstore(ws + OFF_C1 + r1, v1 > 0.f ? v1 : 0.f);
      }
    }
    gbar(ws, bar++);
    // ---------- Phase D: g rows {r0,r1} ----------
    {
      float4 ca = ld4c(ws + OFF_C1 + l4);
      float4 cb = ld4c(ws + OFF_C1 + 256 + l4);
      float acc0 = dot4(WC00, ca) + dot4(WC01, cb);
      float acc1 = dot4(WC10, ca) + dot4(WC11, cb);
      acc0 = wred(acc0); acc1 = wred(acc1);
      if (lane == 0) {
        float v0 = acc0 + BC0;
        float v1 = acc1 + BC1;
        gstore(ws + OFF_G + r0, v0 > 0.f ? v0 : 0.f);
        gstore(ws + OFF_G + r1, v1 > 0.f ? v1 : 0.f);
      }
    }
    gbar(ws, bar++);
    // ---------- Phase E: GRU rows {r0,r1} -> h_{s+1} ----------
    {
      float4 ga = ld4c(ws + OFF_G + l4);
      float4 gb = ld4c(ws + OFF_G + 256 + l4);
      float a0 = dot4(WI00, ga) + dot4(WI01, gb);
      float a1 = dot4(WI10, ga) + dot4(WI11, gb);
      float a2 = dot4(WI20, ga) + dot4(WI21, gb);
      float a3 = dot4(WI30, ga) + dot4(WI31, gb);
      float a4_ = dot4(WI40, ga) + dot4(WI41, gb);
      float a5 = dot4(WI50, ga) + dot4(WI51, gb);
      a0 = wred(a0); a1 = wred(a1); a2 = wred(a2);
      a3 = wred(a3); a4_ = wred(a4_); a5 = wred(a5);
      if (lane == 0) {
        float ir0 = a0 + BI0, iz0 = a1 + BI1, in0 = a2 + BI2;
        float rg0 = 1.f / (1.f + expf(-(ir0 + ghr0)));
        float zg0 = 1.f / (1.f + expf(-(iz0 + ghz0)));
        float ng0 = tanhf(in0 + rg0 * ghn0);
        float hp0 = ld1c(ws + OFF_HS + s * HDIM + r0);
        gstore(ws + OFF_HS + (s + 1) * HDIM + r0, (1.f - zg0) * ng0 + zg0 * hp0);
        float ir1 = a3 + BI3, iz1 = a4_ + BI4, in1 = a5 + BI5;
        float rg1 = 1.f / (1.f + expf(-(ir1 + ghr1)));
        float zg1 = 1.f / (1.f + expf(-(iz1 + ghz1)));
        float ng1 = tanhf(in1 + rg1 * ghn1);
        float hp1 = ld1c(ws + OFF_HS + s * HDIM + r1);
        gstore(ws + OFF_HS + (s + 1) * HDIM + r1, (1.f - zg1) * ng1 + zg1 * hp1);
      }
    }
    gbar(ws, bar++);
  }
}

// logits GEMM v7: 128 threads (2 waves), 256 rows/block, 2 rows/thread.
// Halves the per-row LDS issue vs k_final2: the 152 h-broadcast ds_reads per
// chunk are per-wave-fixed, so covering 128 rows/wave instead of 64 cuts
// per-CU LDS issue ~2x. Proven conflict-free WL layout; same 197-block grid.
#define WL(row, q) ((q) * 1032 + 4 * (row))
__global__ void __launch_bounds__(128) k_final7(const float* __restrict__ ow,
                                                const float* __restrict__ ob,
                                                const float* __restrict__ ws,
                                                float* __restrict__ out) {
  __shared__ __align__(16) float wl[8 * 1032];
  __shared__ __align__(16) float hl[T_STEPS * 512];
  int tid = threadIdx.x;                 // 0..127
  long rbase = (long)blockIdx.x * 256;
  // stage h[1..19] as float4s
  for (int j = tid; j < T_STEPS * 128; j += 128)
    *(float4*)&hl[4 * j] = *(const float4*)(ws + OFF_HS + 512 + 4 * j);
  float4 st[16];
#pragma unroll
  for (int i = 0; i < 16; ++i) {
    int f = tid + 128 * i; int row = f >> 3, q = f & 7;
    long r = rbase + row;
    st[i] = (r < V) ? *(const float4*)(ow + r * 512 + 4 * q) : make_float4(0.f, 0.f, 0.f, 0.f);
  }
  float acc0[T_STEPS], acc1[T_STEPS];
#pragma unroll
  for (int s = 0; s < T_STEPS; ++s) { acc0[s] = 0.f; acc1[s] = 0.f; }
  __syncthreads();  // hl ready
  for (int c = 0; c < 16; ++c) {
#pragma unroll
    for (int i = 0; i < 16; ++i) {
      int f = tid + 128 * i; int row = f >> 3, q = f & 7;
      *(float4*)(&wl[WL(row, q)]) = st[i];
    }
    __syncthreads();  // wl ready
    if (c < 15) {
#pragma unroll
      for (int i = 0; i < 16; ++i) {
        int f = tid + 128 * i; int row = f >> 3, q = f & 7;
        long r = rbase + row;
        st[i] = (r < V) ? *(const float4*)(ow + r * 512 + (c + 1) * 32 + 4 * q) : make_float4(0.f, 0.f, 0.f, 0.f);
      }
    }
    // compute: thread owns rows {tid, tid+128}
#pragma unroll
    for (int kq = 0; kq < 8; ++kq) {
      float4 w4a = *(const float4*)(&wl[WL(tid, kq)]);
      float4 w4b = *(const float4*)(&wl[WL(tid + 128, kq)]);
      const float* hb = hl + c * 32 + 4 * kq;
#pragma unroll
      for (int s = 0; s < T_STEPS; ++s) {
        float4 h4 = *(const float4*)(hb + s * 512);
        acc0[s] += dot4(w4a, h4);
        acc1[s] += dot4(w4b, h4);
      }
    }
    __syncthreads();  // done reading wl
  }
  long ra = rbase + tid;
  if (ra < V) {
    float b = ob[ra];
#pragma unroll
    for (int s = 0; s < T_STEPS; ++s) out[OUT_LOGITS + (long)s * V + ra] = acc0[s] + b;
  }
  long rb = rbase + 128 + tid;
  if (rb < V) {
    float b = ob[rb];
#pragma unroll
    for (int s = 0; s < T_STEPS; ++s) out[OUT_LOGITS + (long)s * V + rb] = acc1[s] + b;
  }
}

extern "C" void kernel_launch(void* const* d_in, const int* in_sizes, int n_in,
                              void* d_out, int out_size, void* d_ws, size_t ws_size,
                              hipStream_t stream) {
  const int*   input_tok  = (const int*)d_in[0];
  const float* hidden     = (const float*)d_in[1];
  const float* enc        = (const float*)d_in[2];
  const float* prop       = (const float*)d_in[3];
  const int*   obj_mask   = (const int*)d_in[4];
  const int*   lang_mask  = (const int*)d_in[5];
  const int*   ans        = (const int*)d_in[6];
  const float* emb        = (const float*)d_in[7];
  const float* attn_w1    = (const float*)d_in[8];
  const float* attn_b1    = (const float*)d_in[9];
  const float* attn_w2    = (const float*)d_in[10];
  const float* attn_b2    = (const float*)d_in[11];
  const float* attn_op_w1 = (const float*)d_in[12];
  const float* attn_op_b1 = (const float*)d_in[13];
  const float* attn_op_w2 = (const float*)d_in[14];
  const float* attn_op_b2 = (const float*)d_in[15];
  const float* cmb_w1     = (const float*)d_in[16];
  const float* cmb_b1     = (const float*)d_in[17];
  const float* cmb_w2     = (const float*)d_in[18];
  const float* cmb_b2     = (const float*)d_in[19];
  const float* gw_ih      = (const float*)d_in[20];
  const float* gw_hh      = (const float*)d_in[21];
  const float* gb_ih      = (const float*)d_in[22];
  const float* gb_hh      = (const float*)d_in[23];
  const float* out_w      = (const float*)d_in[24];
  const float* out_b      = (const float*)d_in[25];
  float* out = (float*)d_out;
  float* ws  = (float*)d_ws;

  // reset the 64 barrier flags (64B stride; monotonic; first barrier index is 1)
  hipMemsetAsync((char*)d_ws + (size_t)OFF_BAR * 4, 0, 4608, stream);
  k_pre1<<<25, 256, 0, stream>>>(input_tok, ans, emb, hidden, ws);
  k_pre2<<<4864, 256, 0, stream>>>(attn_op_w1, attn_op_b1, attn_w1, attn_b1, cmb_w1, cmb_b1, ws);
  k_mprep<<<512, 256, 0, stream>>>(cmb_w1, prop, enc, ws);
  k_recur<<<NBLK, 256, 0, stream>>>(attn_op_w1, attn_w1, gw_hh, gb_hh,
                                    attn_op_w2, attn_op_b2, attn_w2, attn_b2,
                                    obj_mask, lang_mask, cmb_w2, cmb_b2,
                                    gw_ih, gb_ih, ws, out);
  k_final7<<<(V + 255) / 256, 128, 0, stream>>>(out_w, out_b, ws, out);
}

// Round 16
// 502.450 us; speedup vs baseline: 1.0203x; 1.0203x over previous
//
#include <hip/hip_runtime.h>
#include <math.h>

#define T_STEPS 19
#define V 50257
#define EMB 300
#define HDIM 512
#define NP 256
#define ML 50
#define CIN 812
#define NEGV -1e9f
#define NBLK 64

// ---- workspace layout (float indices) ----
#define OFF_X      0                         // 19*300
#define OFF_POP    5700                      // 19*256
#define OFF_PL     10564                     // 19*256
#define OFF_PC     15428                     // 19*512
#define OFF_HS     25156                     // 20*512
#define OFF_H1OP   35396                     // 256
#define OFF_H1L    35652                     // 256
#define OFF_C1     35908                     // 512
#define OFF_G      36420                     // 512
#define OFF_LOGOP  36932                     // 256
#define OFF_LOGL   37188                     // 64
#define OFF_MPROP  37252                     // 512*256 = 131072
#define OFF_MENC   168324                    // 512*50  = 25600
#define OFF_BAR    193924                    // flags @ +16 + 16*b (64B stride — proven R9)

// ---- output layout (floats) ----
#define OUT_LOGITS 0
#define OUT_ATTW   ((long)T_STEPS * V)
#define OUT_ATTOB  (OUT_ATTW + (long)T_STEPS * ML)

__device__ __forceinline__ float wred(float v) {
  v += __shfl_xor(v, 32, 64);
  v += __shfl_xor(v, 16, 64);
  v += __shfl_xor(v, 8, 64);
  v += __shfl_xor(v, 4, 64);
  v += __shfl_xor(v, 2, 64);
  v += __shfl_xor(v, 1, 64);
  return v;
}

__device__ __forceinline__ float dot4(float4 a, float4 b) {
  return a.x * b.x + a.y * b.y + a.z * b.z + a.w * b.w;
}

// ---- agent-coherent access (bypass non-coherent L1/L2; hit the MALL) ----
__device__ __forceinline__ void gstore(float* p, float v) {
  __hip_atomic_store(p, v, __ATOMIC_RELAXED, __HIP_MEMORY_SCOPE_AGENT);
}
__device__ __forceinline__ float ld1c(const float* p) {
  return __hip_atomic_load(p, __ATOMIC_RELAXED, __HIP_MEMORY_SCOPE_AGENT);
}
__device__ __forceinline__ float2 ld2c(const float* p) {
  unsigned long long u = __hip_atomic_load((const unsigned long long*)p,
                                           __ATOMIC_RELAXED, __HIP_MEMORY_SCOPE_AGENT);
  float2 r;
  r.x = __uint_as_float((unsigned)u);
  r.y = __uint_as_float((unsigned)(u >> 32));
  return r;
}
__device__ __forceinline__ float4 ld4c(const float* p) {
  float2 a = ld2c(p), b = ld2c(p + 2);
  return make_float4(a.x, a.y, b.x, b.y);
}

// All-poll-all fence-free grid barrier (proven R9/R12, 64B-stride flags):
// each block stores its flag; every block's wave-0 lanes poll all 64 flags.
__device__ __forceinline__ void gbar(float* wsb, unsigned bar) {
  asm volatile("s_waitcnt vmcnt(0)" ::: "memory");
  __syncthreads();
  unsigned* flags = (unsigned*)(wsb + OFF_BAR) + 16;
  if (threadIdx.x == 0) {
    __hip_atomic_store(flags + 16 * blockIdx.x, bar, __ATOMIC_RELAXED, __HIP_MEMORY_SCOPE_AGENT);
  }
  asm volatile("" ::: "memory");
  if (threadIdx.x < 64) {
    unsigned* f = flags + 16 * threadIdx.x;
    while (__hip_atomic_load(f, __ATOMIC_RELAXED, __HIP_MEMORY_SCOPE_AGENT) < bar) {
      __builtin_amdgcn_s_sleep(1);
    }
  }
  __syncthreads();
}

// Precompute X = relu(emb[token]) for all steps; copy Hs[0].
__global__ void k_pre1(const int* __restrict__ tok0, const int* __restrict__ ans,
                       const float* __restrict__ emb, const float* __restrict__ hidden,
                       float* __restrict__ ws) {
  int tid = blockIdx.x * 256 + threadIdx.x;
  if (tid < T_STEPS * EMB) {
    int s = tid / EMB, j = tid - s * EMB;
    int t = (s == 0) ? tok0[0] : ans[s];
    float v = emb[(long)t * EMB + j];
    ws[OFF_X + tid] = v > 0.f ? v : 0.f;
  } else {
    int k = tid - T_STEPS * EMB;
    if (k < HDIM) ws[OFF_HS + k] = hidden[k];
  }
}

// P_op/P_l/P_c: x-column partials + layer-1 biases. wave-per-row, 19*1024 rows.
__global__ void k_pre2(const float* __restrict__ w1op, const float* __restrict__ b1op,
                       const float* __restrict__ w1l,  const float* __restrict__ b1l,
                       const float* __restrict__ wc1,  const float* __restrict__ bc1,
                       float* __restrict__ ws) {
  int gw = (blockIdx.x * 256 + threadIdx.x) >> 6;
  int lane = threadIdx.x & 63;
  int s = gw >> 10;
  int rr = gw & 1023;
  if (s >= T_STEPS) return;
  const float* wrow; const float* bias; float* dst; int r;
  if (rr < 256)      { r = rr;       wrow = w1op + (long)r * CIN; bias = b1op; dst = ws + OFF_POP + s * 256 + r; }
  else if (rr < 512) { r = rr - 256; wrow = w1l  + (long)r * CIN; bias = b1l;  dst = ws + OFF_PL  + s * 256 + r; }
  else               { r = rr - 512; wrow = wc1  + (long)r * CIN; bias = bc1;  dst = ws + OFF_PC  + s * 512 + r; }
  const float* x = ws + OFF_X + s * EMB;
  float acc = 0.f;
#pragma unroll
  for (int it = 0; it < 5; ++it) {
    int j = it * 64 + lane;
    if (j < EMB) acc += wrow[j] * x[j];
  }
  acc = wred(acc);
  if (lane == 0) *dst = acc + bias[r];
}

// M_prop[r][p] = sum_k cmb_w1[r][556+k]*prop[p][k]; M_enc[r][j] = sum_k cmb_w1[r][300+k]*enc[j][k]
#define LDSF 12850
__global__ void __launch_bounds__(256) k_mprep(const float* __restrict__ cw1,
                                               const float* __restrict__ prop,
                                               const float* __restrict__ enc,
                                               float* __restrict__ ws) {
  __shared__ float lds[LDSF];
  int tid = threadIdx.x, r = blockIdx.x;
  float acc = 0.f;
  for (int kc = 0; kc < 8; ++kc) {
    __syncthreads();
#pragma unroll
    for (int i = 0; i < 8; ++i) {
      int f = tid + 256 * i; int row = f >> 3, q = f & 7;
      float4 v = *(const float4*)(prop + (long)row * 256 + kc * 32 + 4 * q);
      float* p = lds + row * 33 + 4 * q;
      p[0] = v.x; p[1] = v.y; p[2] = v.z; p[3] = v.w;
    }
    __syncthreads();
    const float* wbase = cw1 + (long)r * CIN + 556 + kc * 32;
    const float* pl = lds + tid * 33;
#pragma unroll
    for (int k4 = 0; k4 < 8; ++k4) {
      float4 w4 = *(const float4*)(wbase + 4 * k4);
      const float* pp = pl + 4 * k4;
      acc += w4.x * pp[0] + w4.y * pp[1] + w4.z * pp[2] + w4.w * pp[3];
    }
  }
  ws[OFF_MPROP + (long)r * 256 + tid] = acc;
  __syncthreads();
  for (int i = 0; i < 13; ++i) {
    int f = tid + 256 * i;
    if (f < 3200) {
      int row = f >> 6, q = f & 63;
      float4 v = *(const float4*)(enc + (long)row * 256 + 4 * q);
      float* p = lds + row * 257 + 4 * q;
      p[0] = v.x; p[1] = v.y; p[2] = v.z; p[3] = v.w;
    }
  }
  __syncthreads();
  if (tid < ML) {
    const float* wb2 = cw1 + (long)r * CIN + 300;
    const float* el = lds + tid * 257;
    float a2 = 0.f;
#pragma unroll 8
    for (int k = 0; k < 256; ++k) a2 += wb2[k] * el[k];
    ws[OFF_MENC + (long)r * ML + tid] = a2;
  }
}

// Persistent fused recurrence (R9 verbatim): 5 hops/step, 64B-stride flag barrier,
// ALL step-invariant weights in registers. 64 blocks x 256 threads.
__global__ void __launch_bounds__(256, 1) k_recur(
    const float* __restrict__ w1op, const float* __restrict__ w1l,
    const float* __restrict__ whh,  const float* __restrict__ bhh,
    const float* __restrict__ w2op, const float* __restrict__ b2op,
    const float* __restrict__ w2l,  const float* __restrict__ b2l,
    const int* __restrict__ obj_mask, const int* __restrict__ lang_mask,
    const float* __restrict__ wc2,  const float* __restrict__ bc2,
    const float* __restrict__ wih,  const float* __restrict__ bih,
    float* ws, float* __restrict__ out) {
  const int tid = threadIdx.x;
  const int lane = tid & 63;
  const int wv = (blockIdx.x << 2) + (tid >> 6);   // 0..255
  const int r0 = 2 * wv, r1 = 2 * wv + 1;          // owned rows 0..511
  const int l4 = 4 * lane;
  unsigned bar = 1;
  __shared__ float red[256];
  __shared__ __align__(16) float sm_aop[256];
  __shared__ float sm_al[64];

  // ---- one-time register preload of step-invariant weight slices ----
  const float* wa0p = (r0 < 256) ? (w1op + (long)r0 * CIN + 300) : (w1l + (long)(r0 - 256) * CIN + 300);
  const float* wa1p = (r1 < 256) ? (w1op + (long)r1 * CIN + 300) : (w1l + (long)(r1 - 256) * CIN + 300);
  float4 WA00 = *(const float4*)(wa0p + l4), WA01 = *(const float4*)(wa0p + 256 + l4);
  float4 WA10 = *(const float4*)(wa1p + l4), WA11 = *(const float4*)(wa1p + 256 + l4);
  const float* q;
  q = whh + (long)r0 * HDIM;           float4 WH00 = *(const float4*)(q + l4), WH01 = *(const float4*)(q + 256 + l4);
  q = whh + (long)(r0 + 512) * HDIM;   float4 WH10 = *(const float4*)(q + l4), WH11 = *(const float4*)(q + 256 + l4);
  q = whh + (long)(r0 + 1024) * HDIM;  float4 WH20 = *(const float4*)(q + l4), WH21 = *(const float4*)(q + 256 + l4);
  q = whh + (long)r1 * HDIM;           float4 WH30 = *(const float4*)(q + l4), WH31 = *(const float4*)(q + 256 + l4);
  q = whh + (long)(r1 + 512) * HDIM;   float4 WH40 = *(const float4*)(q + l4), WH41 = *(const float4*)(q + 256 + l4);
  q = whh + (long)(r1 + 1024) * HDIM;  float4 WH50 = *(const float4*)(q + l4), WH51 = *(const float4*)(q + 256 + l4);
  float4 W2  = *(const float4*)(w2op + (long)wv * 256 + l4);
  float4 W2L = (wv < ML) ? *(const float4*)(w2l + (long)wv * 256 + l4) : make_float4(0.f, 0.f, 0.f, 0.f);
  float4 MP0 = *(const float4*)(ws + OFF_MPROP + (long)r0 * 256 + l4);
  float4 MP1 = *(const float4*)(ws + OFF_MPROP + (long)r1 * 256 + l4);
  float  ME0 = (lane < ML) ? ws[OFF_MENC + (long)r0 * ML + lane] : 0.f;
  float  ME1 = (lane < ML) ? ws[OFF_MENC + (long)r1 * ML + lane] : 0.f;
  q = wc2 + (long)r0 * HDIM;           float4 WC00 = *(const float4*)(q + l4), WC01 = *(const float4*)(q + 256 + l4);
  q = wc2 + (long)r1 * HDIM;           float4 WC10 = *(const float4*)(q + l4), WC11 = *(const float4*)(q + 256 + l4);
  q = wih + (long)r0 * HDIM;           float4 WI00 = *(const float4*)(q + l4), WI01 = *(const float4*)(q + 256 + l4);
  q = wih + (long)(r0 + 512) * HDIM;   float4 WI10 = *(const float4*)(q + l4), WI11 = *(const float4*)(q + 256 + l4);
  q = wih + (long)(r0 + 1024) * HDIM;  float4 WI20 = *(const float4*)(q + l4), WI21 = *(const float4*)(q + 256 + l4);
  q = wih + (long)r1 * HDIM;           float4 WI30 = *(const float4*)(q + l4), WI31 = *(const float4*)(q + 256 + l4);
  q = wih + (long)(r1 + 512) * HDIM;   float4 WI40 = *(const float4*)(q + l4), WI41 = *(const float4*)(q + 256 + l4);
  q = wih + (long)(r1 + 1024) * HDIM;  float4 WI50 = *(const float4*)(q + l4), WI51 = *(const float4*)(q + 256 + l4);
  float BH0 = bhh[r0], BH1 = bhh[512 + r0], BH2 = bhh[1024 + r0];
  float BH3 = bhh[r1], BH4 = bhh[512 + r1], BH5 = bhh[1024 + r1];
  float BI0 = bih[r0], BI1 = bih[512 + r0], BI2 = bih[1024 + r0];
  float BI3 = bih[r1], BI4 = bih[512 + r1], BI5 = bih[1024 + r1];
  float BC0 = bc2[r0], BC1 = bc2[r1];
  float B2  = b2op[wv];
  float B2Lv = (wv < ML) ? b2l[wv] : 0.f;

  for (int s = 0; s < T_STEPS; ++s) {
    float ghr0, ghz0, ghn0, ghr1, ghz1, ghn1;
    // ---------- Phase A: h1 rows {r0,r1}; gh -> regs ----------
    {
      const float* h = ws + OFF_HS + s * HDIM;
      float4 ha = ld4c(h + l4);
      float4 hb = ld4c(h + 256 + l4);
      float a0 = dot4(WA00, ha) + dot4(WA01, hb);
      float a1 = dot4(WA10, ha) + dot4(WA11, hb);
      float b0 = dot4(WH00, ha) + dot4(WH01, hb);
      float b1 = dot4(WH10, ha) + dot4(WH11, hb);
      float b2 = dot4(WH20, ha) + dot4(WH21, hb);
      float b3 = dot4(WH30, ha) + dot4(WH31, hb);
      float b4 = dot4(WH40, ha) + dot4(WH41, hb);
      float b5 = dot4(WH50, ha) + dot4(WH51, hb);
      a0 = wred(a0); a1 = wred(a1);
      b0 = wred(b0); b1 = wred(b1); b2 = wred(b2);
      b3 = wred(b3); b4 = wred(b4); b5 = wred(b5);
      ghr0 = b0 + BH0; ghz0 = b1 + BH1; ghn0 = b2 + BH2;
      ghr1 = b3 + BH3; ghz1 = b4 + BH4; ghn1 = b5 + BH5;
      if (lane == 0) {
        float v0 = a0 + ((r0 < 256) ? ws[OFF_POP + s * 256 + r0] : ws[OFF_PL + s * 256 + (r0 - 256)]);
        float v1 = a1 + ((r1 < 256) ? ws[OFF_POP + s * 256 + r1] : ws[OFF_PL + s * 256 + (r1 - 256)]);
        float* d0 = (r0 < 256) ? (ws + OFF_H1OP + r0) : (ws + OFF_H1L + (r0 - 256));
        float* d1 = (r1 < 256) ? (ws + OFF_H1OP + r1) : (ws + OFF_H1L + (r1 - 256));
        gstore(d0, v0 > 0.f ? v0 : 0.f);
        gstore(d1, v1 > 0.f ? v1 : 0.f);
      }
    }
    gbar(ws, bar++);
    // ---------- Phase B: attention logits ----------
    {
      float4 h1 = ld4c(ws + OFF_H1OP + l4);
      float acc = wred(dot4(W2, h1));
      if (lane == 0) gstore(ws + OFF_LOGOP + wv, acc + B2);
      if (wv < ML) {
        float4 h1l = ld4c(ws + OFF_H1L + l4);
        float accl = wred(dot4(W2L, h1l));
        if (lane == 0) gstore(ws + OFF_LOGL + wv, accl + B2Lv);
      }
    }
    gbar(ws, bar++);
    // ---------- Phase C: block-redundant softmax + c1 rows {r0,r1} ----------
    {
      float lv = ld1c(ws + OFF_LOGOP + tid);
      float vo = (obj_mask[tid] != 0) ? NEGV : lv;
      red[tid] = vo; __syncthreads();
      for (int st = 128; st > 0; st >>= 1) { if (tid < st) red[tid] = fmaxf(red[tid], red[tid + st]); __syncthreads(); }
      float mo = red[0]; __syncthreads();
      float eo = expf(vo - mo);
      red[tid] = eo; __syncthreads();
      for (int st = 128; st > 0; st >>= 1) { if (tid < st) red[tid] += red[tid + st]; __syncthreads(); }
      float aop = eo / red[0];
      sm_aop[tid] = aop;
      __syncthreads();
      float ll = 0.f;
      if (tid < ML) ll = ld1c(ws + OFF_LOGL + tid);
      float vl = (tid < ML) ? ((lang_mask[tid] != 0) ? NEGV : ll) : -3e38f;
      red[tid] = vl; __syncthreads();
      for (int st = 128; st > 0; st >>= 1) { if (tid < st) red[tid] = fmaxf(red[tid], red[tid + st]); __syncthreads(); }
      float ml_ = red[0]; __syncthreads();
      float el = (tid < ML) ? expf(vl - ml_) : 0.f;
      red[tid] = el; __syncthreads();
      for (int st = 128; st > 0; st >>= 1) { if (tid < st) red[tid] += red[tid + st]; __syncthreads(); }
      float al = el / red[0];
      if (tid < 64) sm_al[tid] = (tid < ML) ? al : 0.f;
      __syncthreads();
      if (blockIdx.x == 0) {
        out[OUT_ATTOB + (long)s * NP + tid] = aop;
        if (tid < ML) out[OUT_ATTW + (long)s * ML + tid] = al;
      }
      float4 a4 = *(const float4*)(&sm_aop[l4]);
      float acc0 = dot4(MP0, a4);
      float acc1 = dot4(MP1, a4);
      if (lane < ML) {
        float alv = sm_al[lane];
        acc0 += ME0 * alv;
        acc1 += ME1 * alv;
      }
      acc0 = wred(acc0); acc1 = wred(acc1);
      if (lane == 0) {
        float v0 = acc0 + ws[OFF_PC + s * HDIM + r0];
        float v1 = acc1 + ws[OFF_PC + s * HDIM + r1];
        gstore(ws + OFF_C1 + r0, v0 > 0.f ? v0 : 0.f);
        gstore(ws + OFF_C1 + r1, v1 > 0.f ? v1 : 0.f);
      }
    }
    gbar(ws, bar++);
    // ---------- Phase D: g rows {r0,r1} ----------
    {
      float4 ca = ld4c(ws + OFF_C1 + l4);
      float4 cb = ld4c(ws + OFF_C1 + 256 + l4);
      float acc0 = dot4(WC00, ca) + dot4(WC01, cb);
      float acc1 = dot4(WC10, ca) + dot4(WC11, cb);
      acc0 = wred(acc0); acc1 = wred(acc1);
      if (lane == 0) {
        float v0 = acc0 + BC0;
        float v1 = acc1 + BC1;
        gstore(ws + OFF_G + r0, v0 > 0.f ? v0 : 0.f);
        gstore(ws + OFF_G + r1, v1 > 0.f ? v1 : 0.f);
      }
    }
    gbar(ws, bar++);
    // ---------- Phase E: GRU rows {r0,r1} -> h_{s+1} ----------
    {
      float4 ga = ld4c(ws + OFF_G + l4);
      float4 gb = ld4c(ws + OFF_G + 256 + l4);
      float a0 = dot4(WI00, ga) + dot4(WI01, gb);
      float a1 = dot4(WI10, ga) + dot4(WI11, gb);
      float a2 = dot4(WI20, ga) + dot4(WI21, gb);
      float a3 = dot4(WI30, ga) + dot4(WI31, gb);
      float a4_ = dot4(WI40, ga) + dot4(WI41, gb);
      float a5 = dot4(WI50, ga) + dot4(WI51, gb);
      a0 = wred(a0); a1 = wred(a1); a2 = wred(a2);
      a3 = wred(a3); a4_ = wred(a4_); a5 = wred(a5);
      if (lane == 0) {
        float ir0 = a0 + BI0, iz0 = a1 + BI1, in0 = a2 + BI2;
        float rg0 = 1.f / (1.f + expf(-(ir0 + ghr0)));
        float zg0 = 1.f / (1.f + expf(-(iz0 + ghz0)));
        float ng0 = tanhf(in0 + rg0 * ghn0);
        float hp0 = ld1c(ws + OFF_HS + s * HDIM + r0);
        gstore(ws + OFF_HS + (s + 1) * HDIM + r0, (1.f - zg0) * ng0 + zg0 * hp0);
        float ir1 = a3 + BI3, iz1 = a4_ + BI4, in1 = a5 + BI5;
        float rg1 = 1.f / (1.f + expf(-(ir1 + ghr1)));
        float zg1 = 1.f / (1.f + expf(-(iz1 + ghz1)));
        float ng1 = tanhf(in1 + rg1 * ghn1);
        float hp1 = ld1c(ws + OFF_HS + s * HDIM + r1);
        gstore(ws + OFF_HS + (s + 1) * HDIM + r1, (1.f - zg1) * ng1 + zg1 * hp1);
      }
    }
    gbar(ws, bar++);
  }
}

// logits GEMM v8: 256 threads (4 waves), 512 rows/block, 2 rows/thread
// (rows tid in wla, tid+256 in wlb). Both w-buffers use the proven
// conflict-free WL layout; 152 h-broadcasts/chunk now serve 128 rows/wave
// (2x amortization vs k_final2) while keeping 4 waves for HBM latency hiding.
// LDS: 2*33KB (wla,wlb) + 38.9KB (hl) = 102.5KB; 99 blocks.
#define WL(row, q) ((q) * 1032 + 4 * (row))
__global__ void __launch_bounds__(256) k_final8(const float* __restrict__ ow,
                                                const float* __restrict__ ob,
                                                const float* __restrict__ ws,
                                                float* __restrict__ out) {
  __shared__ __align__(16) float wla[8 * 1032];
  __shared__ __align__(16) float wlb[8 * 1032];
  __shared__ __align__(16) float hl[T_STEPS * 512];
  int tid = threadIdx.x;
  long rbase = (long)blockIdx.x * 512;
  for (int i = tid; i < T_STEPS * 512; i += 256) hl[i] = ws[OFF_HS + 512 + i];
  float4 st[16];
#pragma unroll
  for (int i = 0; i < 16; ++i) {
    int f = tid + 256 * i; int row = f >> 3, q = f & 7;
    long r = rbase + row;
    st[i] = (r < V) ? *(const float4*)(ow + r * 512 + 4 * q) : make_float4(0.f, 0.f, 0.f, 0.f);
  }
  float acc0[T_STEPS], acc1[T_STEPS];
#pragma unroll
  for (int s = 0; s < T_STEPS; ++s) { acc0[s] = 0.f; acc1[s] = 0.f; }
  __syncthreads();  // hl ready
  for (int c = 0; c < 16; ++c) {
#pragma unroll
    for (int i = 0; i < 8; ++i) {
      int f = tid + 256 * i; int row = f >> 3, q = f & 7;
      *(float4*)(&wla[WL(row, q)]) = st[i];
    }
#pragma unroll
    for (int i = 8; i < 16; ++i) {
      int f = tid + 256 * i; int row = (f >> 3) - 256, q = f & 7;
      *(float4*)(&wlb[WL(row, q)]) = st[i];
    }
    __syncthreads();  // w buffers ready
    if (c < 15) {
#pragma unroll
      for (int i = 0; i < 16; ++i) {
        int f = tid + 256 * i; int row = f >> 3, q = f & 7;
        long r = rbase + row;
        st[i] = (r < V) ? *(const float4*)(ow + r * 512 + (c + 1) * 32 + 4 * q) : make_float4(0.f, 0.f, 0.f, 0.f);
      }
    }
    // compute: thread owns rows {tid (wla), tid+256 (wlb)}
#pragma unroll
    for (int kq = 0; kq < 8; ++kq) {
      float4 w4a = *(const float4*)(&wla[WL(tid, kq)]);
      float4 w4b = *(const float4*)(&wlb[WL(tid, kq)]);
      const float* hb = hl + c * 32 + 4 * kq;
#pragma unroll
      for (int s = 0; s < T_STEPS; ++s) {
        float4 h4 = *(const float4*)(hb + s * 512);
        acc0[s] += dot4(w4a, h4);
        acc1[s] += dot4(w4b, h4);
      }
    }
    __syncthreads();  // done reading w buffers
  }
  long ra = rbase + tid;
  if (ra < V) {
    float b = ob[ra];
#pragma unroll
    for (int s = 0; s < T_STEPS; ++s) out[OUT_LOGITS + (long)s * V + ra] = acc0[s] + b;
  }
  long rb = rbase + 256 + tid;
  if (rb < V) {
    float b = ob[rb];
#pragma unroll
    for (int s = 0; s < T_STEPS; ++s) out[OUT_LOGITS + (long)s * V + rb] = acc1[s] + b;
  }
}

extern "C" void kernel_launch(void* const* d_in, const int* in_sizes, int n_in,
                              void* d_out, int out_size, void* d_ws, size_t ws_size,
                              hipStream_t stream) {
  const int*   input_tok  = (const int*)d_in[0];
  const float* hidden     = (const float*)d_in[1];
  const float* enc        = (const float*)d_in[2];
  const float* prop       = (const float*)d_in[3];
  const int*   obj_mask   = (const int*)d_in[4];
  const int*   lang_mask  = (const int*)d_in[5];
  const int*   ans        = (const int*)d_in[6];
  const float* emb        = (const float*)d_in[7];
  const float* attn_w1    = (const float*)d_in[8];
  const float* attn_b1    = (const float*)d_in[9];
  const float* attn_w2    = (const float*)d_in[10];
  const float* attn_b2    = (const float*)d_in[11];
  const float* attn_op_w1 = (const float*)d_in[12];
  const float* attn_op_b1 = (const float*)d_in[13];
  const float* attn_op_w2 = (const float*)d_in[14];
  const float* attn_op_b2 = (const float*)d_in[15];
  const float* cmb_w1     = (const float*)d_in[16];
  const float* cmb_b1     = (const float*)d_in[17];
  const float* cmb_w2     = (const float*)d_in[18];
  const float* cmb_b2     = (const float*)d_in[19];
  const float* gw_ih      = (const float*)d_in[20];
  const float* gw_hh      = (const float*)d_in[21];
  const float* gb_ih      = (const float*)d_in[22];
  const float* gb_hh      = (const float*)d_in[23];
  const float* out_w      = (const float*)d_in[24];
  const float* out_b      = (const float*)d_in[25];
  float* out = (float*)d_out;
  float* ws  = (float*)d_ws;

  // reset the 64 barrier flags (64B stride; monotonic; first barrier index is 1)
  hipMemsetAsync((char*)d_ws + (size_t)OFF_BAR * 4, 0, 4608, stream);
  k_pre1<<<25, 256, 0, stream>>>(input_tok, ans, emb, hidden, ws);
  k_pre2<<<4864, 256, 0, stream>>>(attn_op_w1, attn_op_b1, attn_w1, attn_b1, cmb_w1, cmb_b1, ws);
  k_mprep<<<512, 256, 0, stream>>>(cmb_w1, prop, enc, ws);
  k_recur<<<NBLK, 256, 0, stream>>>(attn_op_w1, attn_w1, gw_hh, gb_hh,
                                    attn_op_w2, attn_op_b2, attn_w2, attn_b2,
                                    obj_mask, lang_mask, cmb_w2, cmb_b2,
                                    gw_ih, gb_ih, ws, out);
  k_final8<<<(V + 511) / 512, 256, 0, stream>>>(out_w, out_b, ws, out);
}

// Round 17
// 386.370 us; speedup vs baseline: 1.3268x; 1.3004x over previous
//
#include <hip/hip_runtime.h>
#include <math.h>

#define T_STEPS 19
#define V 50257
#define EMB 300
#define HDIM 512
#define NP 256
#define ML 50
#define CIN 812
#define NEGV -1e9f
#define NBLK 64

// ---- workspace layout (float indices) ----
#define OFF_X      0                         // 19*300
#define OFF_POP    5700                      // 19*256
#define OFF_PL     10564                     // 19*256
#define OFF_PC     15428                     // 19*512
#define OFF_HS     25156                     // 20*512
#define OFF_H1OP   35396                     // 256
#define OFF_H1L    35652                     // 256
#define OFF_C1     35908                     // 512
#define OFF_G      36420                     // 512
#define OFF_LOGOP  36932                     // 256
#define OFF_LOGL   37188                     // 64
#define OFF_MPROP  37252                     // 512*256 = 131072
#define OFF_MENC   168324                    // 512*50  = 25600
#define OFF_BAR    193924                    // flags @ +16 + 16*b (64B stride — proven R9)

// ---- output layout (floats) ----
#define OUT_LOGITS 0
#define OUT_ATTW   ((long)T_STEPS * V)
#define OUT_ATTOB  (OUT_ATTW + (long)T_STEPS * ML)

__device__ __forceinline__ float wred(float v) {
  v += __shfl_xor(v, 32, 64);
  v += __shfl_xor(v, 16, 64);
  v += __shfl_xor(v, 8, 64);
  v += __shfl_xor(v, 4, 64);
  v += __shfl_xor(v, 2, 64);
  v += __shfl_xor(v, 1, 64);
  return v;
}

__device__ __forceinline__ float dot4(float4 a, float4 b) {
  return a.x * b.x + a.y * b.y + a.z * b.z + a.w * b.w;
}

// ---- agent-coherent access (bypass non-coherent L1/L2; hit the MALL) ----
__device__ __forceinline__ void gstore(float* p, float v) {
  __hip_atomic_store(p, v, __ATOMIC_RELAXED, __HIP_MEMORY_SCOPE_AGENT);
}
__device__ __forceinline__ float ld1c(const float* p) {
  return __hip_atomic_load(p, __ATOMIC_RELAXED, __HIP_MEMORY_SCOPE_AGENT);
}
__device__ __forceinline__ float2 ld2c(const float* p) {
  unsigned long long u = __hip_atomic_load((const unsigned long long*)p,
                                           __ATOMIC_RELAXED, __HIP_MEMORY_SCOPE_AGENT);
  float2 r;
  r.x = __uint_as_float((unsigned)u);
  r.y = __uint_as_float((unsigned)(u >> 32));
  return r;
}
__device__ __forceinline__ float4 ld4c(const float* p) {
  float2 a = ld2c(p), b = ld2c(p + 2);
  return make_float4(a.x, a.y, b.x, b.y);
}

// All-poll-all fence-free grid barrier (proven R9/R12, 64B-stride flags):
// each block stores its flag; every block's wave-0 lanes poll all 64 flags.
__device__ __forceinline__ void gbar(float* wsb, unsigned bar) {
  asm volatile("s_waitcnt vmcnt(0)" ::: "memory");
  __syncthreads();
  unsigned* flags = (unsigned*)(wsb + OFF_BAR) + 16;
  if (threadIdx.x == 0) {
    __hip_atomic_store(flags + 16 * blockIdx.x, bar, __ATOMIC_RELAXED, __HIP_MEMORY_SCOPE_AGENT);
  }
  asm volatile("" ::: "memory");
  if (threadIdx.x < 64) {
    unsigned* f = flags + 16 * threadIdx.x;
    while (__hip_atomic_load(f, __ATOMIC_RELAXED, __HIP_MEMORY_SCOPE_AGENT) < bar) {
      __builtin_amdgcn_s_sleep(1);
    }
  }
  __syncthreads();
}

// Precompute X = relu(emb[token]) for all steps; copy Hs[0].
__global__ void k_pre1(const int* __restrict__ tok0, const int* __restrict__ ans,
                       const float* __restrict__ emb, const float* __restrict__ hidden,
                       float* __restrict__ ws) {
  int tid = blockIdx.x * 256 + threadIdx.x;
  if (tid < T_STEPS * EMB) {
    int s = tid / EMB, j = tid - s * EMB;
    int t = (s == 0) ? tok0[0] : ans[s];
    float v = emb[(long)t * EMB + j];
    ws[OFF_X + tid] = v > 0.f ? v : 0.f;
  } else {
    int k = tid - T_STEPS * EMB;
    if (k < HDIM) ws[OFF_HS + k] = hidden[k];
  }
}

// P_op/P_l/P_c: x-column partials + layer-1 biases. wave-per-row, 19*1024 rows.
__global__ void k_pre2(const float* __restrict__ w1op, const float* __restrict__ b1op,
                       const float* __restrict__ w1l,  const float* __restrict__ b1l,
                       const float* __restrict__ wc1,  const float* __restrict__ bc1,
                       float* __restrict__ ws) {
  int gw = (blockIdx.x * 256 + threadIdx.x) >> 6;
  int lane = threadIdx.x & 63;
  int s = gw >> 10;
  int rr = gw & 1023;
  if (s >= T_STEPS) return;
  const float* wrow; const float* bias; float* dst; int r;
  if (rr < 256)      { r = rr;       wrow = w1op + (long)r * CIN; bias = b1op; dst = ws + OFF_POP + s * 256 + r; }
  else if (rr < 512) { r = rr - 256; wrow = w1l  + (long)r * CIN; bias = b1l;  dst = ws + OFF_PL  + s * 256 + r; }
  else               { r = rr - 512; wrow = wc1  + (long)r * CIN; bias = bc1;  dst = ws + OFF_PC  + s * 512 + r; }
  const float* x = ws + OFF_X + s * EMB;
  float acc = 0.f;
#pragma unroll
  for (int it = 0; it < 5; ++it) {
    int j = it * 64 + lane;
    if (j < EMB) acc += wrow[j] * x[j];
  }
  acc = wred(acc);
  if (lane == 0) *dst = acc + bias[r];
}

// M_prop[r][p] = sum_k cmb_w1[r][556+k]*prop[p][k]; M_enc[r][j] = sum_k cmb_w1[r][300+k]*enc[j][k]
#define LDSF 12850
__global__ void __launch_bounds__(256) k_mprep(const float* __restrict__ cw1,
                                               const float* __restrict__ prop,
                                               const float* __restrict__ enc,
                                               float* __restrict__ ws) {
  __shared__ float lds[LDSF];
  int tid = threadIdx.x, r = blockIdx.x;
  float acc = 0.f;
  for (int kc = 0; kc < 8; ++kc) {
    __syncthreads();
#pragma unroll
    for (int i = 0; i < 8; ++i) {
      int f = tid + 256 * i; int row = f >> 3, q = f & 7;
      float4 v = *(const float4*)(prop + (long)row * 256 + kc * 32 + 4 * q);
      float* p = lds + row * 33 + 4 * q;
      p[0] = v.x; p[1] = v.y; p[2] = v.z; p[3] = v.w;
    }
    __syncthreads();
    const float* wbase = cw1 + (long)r * CIN + 556 + kc * 32;
    const float* pl = lds + tid * 33;
#pragma unroll
    for (int k4 = 0; k4 < 8; ++k4) {
      float4 w4 = *(const float4*)(wbase + 4 * k4);
      const float* pp = pl + 4 * k4;
      acc += w4.x * pp[0] + w4.y * pp[1] + w4.z * pp[2] + w4.w * pp[3];
    }
  }
  ws[OFF_MPROP + (long)r * 256 + tid] = acc;
  __syncthreads();
  for (int i = 0; i < 13; ++i) {
    int f = tid + 256 * i;
    if (f < 3200) {
      int row = f >> 6, q = f & 63;
      float4 v = *(const float4*)(enc + (long)row * 256 + 4 * q);
      float* p = lds + row * 257 + 4 * q;
      p[0] = v.x; p[1] = v.y; p[2] = v.z; p[3] = v.w;
    }
  }
  __syncthreads();
  if (tid < ML) {
    const float* wb2 = cw1 + (long)r * CIN + 300;
    const float* el = lds + tid * 257;
    float a2 = 0.f;
#pragma unroll 8
    for (int k = 0; k < 256; ++k) a2 += wb2[k] * el[k];
    ws[OFF_MENC + (long)r * ML + tid] = a2;
  }
}

// Persistent fused recurrence (R9 verbatim): 5 hops/step, 64B-stride flag barrier,
// ALL step-invariant weights in registers. 64 blocks x 256 threads.
__global__ void __launch_bounds__(256, 1) k_recur(
    const float* __restrict__ w1op, const float* __restrict__ w1l,
    const float* __restrict__ whh,  const float* __restrict__ bhh,
    const float* __restrict__ w2op, const float* __restrict__ b2op,
    const float* __restrict__ w2l,  const float* __restrict__ b2l,
    const int* __restrict__ obj_mask, const int* __restrict__ lang_mask,
    const float* __restrict__ wc2,  const float* __restrict__ bc2,
    const float* __restrict__ wih,  const float* __restrict__ bih,
    float* ws, float* __restrict__ out) {
  const int tid = threadIdx.x;
  const int lane = tid & 63;
  const int wv = (blockIdx.x << 2) + (tid >> 6);   // 0..255
  const int r0 = 2 * wv, r1 = 2 * wv + 1;          // owned rows 0..511
  const int l4 = 4 * lane;
  unsigned bar = 1;
  __shared__ float red[256];
  __shared__ __align__(16) float sm_aop[256];
  __shared__ float sm_al[64];

  // ---- one-time register preload of step-invariant weight slices ----
  const float* wa0p = (r0 < 256) ? (w1op + (long)r0 * CIN + 300) : (w1l + (long)(r0 - 256) * CIN + 300);
  const float* wa1p = (r1 < 256) ? (w1op + (long)r1 * CIN + 300) : (w1l + (long)(r1 - 256) * CIN + 300);
  float4 WA00 = *(const float4*)(wa0p + l4), WA01 = *(const float4*)(wa0p + 256 + l4);
  float4 WA10 = *(const float4*)(wa1p + l4), WA11 = *(const float4*)(wa1p + 256 + l4);
  const float* q;
  q = whh + (long)r0 * HDIM;           float4 WH00 = *(const float4*)(q + l4), WH01 = *(const float4*)(q + 256 + l4);
  q = whh + (long)(r0 + 512) * HDIM;   float4 WH10 = *(const float4*)(q + l4), WH11 = *(const float4*)(q + 256 + l4);
  q = whh + (long)(r0 + 1024) * HDIM;  float4 WH20 = *(const float4*)(q + l4), WH21 = *(const float4*)(q + 256 + l4);
  q = whh + (long)r1 * HDIM;           float4 WH30 = *(const float4*)(q + l4), WH31 = *(const float4*)(q + 256 + l4);
  q = whh + (long)(r1 + 512) * HDIM;   float4 WH40 = *(const float4*)(q + l4), WH41 = *(const float4*)(q + 256 + l4);
  q = whh + (long)(r1 + 1024) * HDIM;  float4 WH50 = *(const float4*)(q + l4), WH51 = *(const float4*)(q + 256 + l4);
  float4 W2  = *(const float4*)(w2op + (long)wv * 256 + l4);
  float4 W2L = (wv < ML) ? *(const float4*)(w2l + (long)wv * 256 + l4) : make_float4(0.f, 0.f, 0.f, 0.f);
  float4 MP0 = *(const float4*)(ws + OFF_MPROP + (long)r0 * 256 + l4);
  float4 MP1 = *(const float4*)(ws + OFF_MPROP + (long)r1 * 256 + l4);
  float  ME0 = (lane < ML) ? ws[OFF_MENC + (long)r0 * ML + lane] : 0.f;
  float  ME1 = (lane < ML) ? ws[OFF_MENC + (long)r1 * ML + lane] : 0.f;
  q = wc2 + (long)r0 * HDIM;           float4 WC00 = *(const float4*)(q + l4), WC01 = *(const float4*)(q + 256 + l4);
  q = wc2 + (long)r1 * HDIM;           float4 WC10 = *(const float4*)(q + l4), WC11 = *(const float4*)(q + 256 + l4);
  q = wih + (long)r0 * HDIM;           float4 WI00 = *(const float4*)(q + l4), WI01 = *(const float4*)(q + 256 + l4);
  q = wih + (long)(r0 + 512) * HDIM;   float4 WI10 = *(const float4*)(q + l4), WI11 = *(const float4*)(q + 256 + l4);
  q = wih + (long)(r0 + 1024) * HDIM;  float4 WI20 = *(const float4*)(q + l4), WI21 = *(const float4*)(q + 256 + l4);
  q = wih + (long)r1 * HDIM;           float4 WI30 = *(const float4*)(q + l4), WI31 = *(const float4*)(q + 256 + l4);
  q = wih + (long)(r1 + 512) * HDIM;   float4 WI40 = *(const float4*)(q + l4), WI41 = *(const float4*)(q + 256 + l4);
  q = wih + (long)(r1 + 1024) * HDIM;  float4 WI50 = *(const float4*)(q + l4), WI51 = *(const float4*)(q + 256 + l4);
  float BH0 = bhh[r0], BH1 = bhh[512 + r0], BH2 = bhh[1024 + r0];
  float BH3 = bhh[r1], BH4 = bhh[512 + r1], BH5 = bhh[1024 + r1];
  float BI0 = bih[r0], BI1 = bih[512 + r0], BI2 = bih[1024 + r0];
  float BI3 = bih[r1], BI4 = bih[512 + r1], BI5 = bih[1024 + r1];
  float BC0 = bc2[r0], BC1 = bc2[r1];
  float B2  = b2op[wv];
  float B2Lv = (wv < ML) ? b2l[wv] : 0.f;

  for (int s = 0; s < T_STEPS; ++s) {
    float ghr0, ghz0, ghn0, ghr1, ghz1, ghn1;
    // ---------- Phase A: h1 rows {r0,r1}; gh -> regs ----------
    {
      const float* h = ws + OFF_HS + s * HDIM;
      float4 ha = ld4c(h + l4);
      float4 hb = ld4c(h + 256 + l4);
      float a0 = dot4(WA00, ha) + dot4(WA01, hb);
      float a1 = dot4(WA10, ha) + dot4(WA11, hb);
      float b0 = dot4(WH00, ha) + dot4(WH01, hb);
      float b1 = dot4(WH10, ha) + dot4(WH11, hb);
      float b2 = dot4(WH20, ha) + dot4(WH21, hb);
      float b3 = dot4(WH30, ha) + dot4(WH31, hb);
      float b4 = dot4(WH40, ha) + dot4(WH41, hb);
      float b5 = dot4(WH50, ha) + dot4(WH51, hb);
      a0 = wred(a0); a1 = wred(a1);
      b0 = wred(b0); b1 = wred(b1); b2 = wred(b2);
      b3 = wred(b3); b4 = wred(b4); b5 = wred(b5);
      ghr0 = b0 + BH0; ghz0 = b1 + BH1; ghn0 = b2 + BH2;
      ghr1 = b3 + BH3; ghz1 = b4 + BH4; ghn1 = b5 + BH5;
      if (lane == 0) {
        float v0 = a0 + ((r0 < 256) ? ws[OFF_POP + s * 256 + r0] : ws[OFF_PL + s * 256 + (r0 - 256)]);
        float v1 = a1 + ((r1 < 256) ? ws[OFF_POP + s * 256 + r1] : ws[OFF_PL + s * 256 + (r1 - 256)]);
        float* d0 = (r0 < 256) ? (ws + OFF_H1OP + r0) : (ws + OFF_H1L + (r0 - 256));
        float* d1 = (r1 < 256) ? (ws + OFF_H1OP + r1) : (ws + OFF_H1L + (r1 - 256));
        gstore(d0, v0 > 0.f ? v0 : 0.f);
        gstore(d1, v1 > 0.f ? v1 : 0.f);
      }
    }
    gbar(ws, bar++);
    // ---------- Phase B: attention logits ----------
    {
      float4 h1 = ld4c(ws + OFF_H1OP + l4);
      float acc = wred(dot4(W2, h1));
      if (lane == 0) gstore(ws + OFF_LOGOP + wv, acc + B2);
      if (wv < ML) {
        float4 h1l = ld4c(ws + OFF_H1L + l4);
        float accl = wred(dot4(W2L, h1l));
        if (lane == 0) gstore(ws + OFF_LOGL + wv, accl + B2Lv);
      }
    }
    gbar(ws, bar++);
    // ---------- Phase C: block-redundant softmax + c1 rows {r0,r1} ----------
    {
      float lv = ld1c(ws + OFF_LOGOP + tid);
      float vo = (obj_mask[tid] != 0) ? NEGV : lv;
      red[tid] = vo; __syncthreads();
      for (int st = 128; st > 0; st >>= 1) { if (tid < st) red[tid] = fmaxf(red[tid], red[tid + st]); __syncthreads(); }
      float mo = red[0]; __syncthreads();
      float eo = expf(vo - mo);
      red[tid] = eo; __syncthreads();
      for (int st = 128; st > 0; st >>= 1) { if (tid < st) red[tid] += red[tid + st]; __syncthreads(); }
      float aop = eo / red[0];
      sm_aop[tid] = aop;
      __syncthreads();
      float ll = 0.f;
      if (tid < ML) ll = ld1c(ws + OFF_LOGL + tid);
      float vl = (tid < ML) ? ((lang_mask[tid] != 0) ? NEGV : ll) : -3e38f;
      red[tid] = vl; __syncthreads();
      for (int st = 128; st > 0; st >>= 1) { if (tid < st) red[tid] = fmaxf(red[tid], red[tid + st]); __syncthreads(); }
      float ml_ = red[0]; __syncthreads();
      float el = (tid < ML) ? expf(vl - ml_) : 0.f;
      red[tid] = el; __syncthreads();
      for (int st = 128; st > 0; st >>= 1) { if (tid < st) red[tid] += red[tid + st]; __syncthreads(); }
      float al = el / red[0];
      if (tid < 64) sm_al[tid] = (tid < ML) ? al : 0.f;
      __syncthreads();
      if (blockIdx.x == 0) {
        out[OUT_ATTOB + (long)s * NP + tid] = aop;
        if (tid < ML) out[OUT_ATTW + (long)s * ML + tid] = al;
      }
      float4 a4 = *(const float4*)(&sm_aop[l4]);
      float acc0 = dot4(MP0, a4);
      float acc1 = dot4(MP1, a4);
      if (lane < ML) {
        float alv = sm_al[lane];
        acc0 += ME0 * alv;
        acc1 += ME1 * alv;
      }
      acc0 = wred(acc0); acc1 = wred(acc1);
      if (lane == 0) {
        float v0 = acc0 + ws[OFF_PC + s * HDIM + r0];
        float v1 = acc1 + ws[OFF_PC + s * HDIM + r1];
        gstore(ws + OFF_C1 + r0, v0 > 0.f ? v0 : 0.f);
        gstore(ws + OFF_C1 + r1, v1 > 0.f ? v1 : 0.f);
      }
    }
    gbar(ws, bar++);
    // ---------- Phase D: g rows {r0,r1} ----------
    {
      float4 ca = ld4c(ws + OFF_C1 + l4);
      float4 cb = ld4c(ws + OFF_C1 + 256 + l4);
      float acc0 = dot4(WC00, ca) + dot4(WC01, cb);
      float acc1 = dot4(WC10, ca) + dot4(WC11, cb);
      acc0 = wred(acc0); acc1 = wred(acc1);
      if (lane == 0) {
        float v0 = acc0 + BC0;
        float v1 = acc1 + BC1;
        gstore(ws + OFF_G + r0, v0 > 0.f ? v0 : 0.f);
        gstore(ws + OFF_G + r1, v1 > 0.f ? v1 : 0.f);
      }
    }
    gbar(ws, bar++);
    // ---------- Phase E: GRU rows {r0,r1} -> h_{s+1} ----------
    {
      float4 ga = ld4c(ws + OFF_G + l4);
      float4 gb = ld4c(ws + OFF_G + 256 + l4);
      float a0 = dot4(WI00, ga) + dot4(WI01, gb);
      float a1 = dot4(WI10, ga) + dot4(WI11, gb);
      float a2 = dot4(WI20, ga) + dot4(WI21, gb);
      float a3 = dot4(WI30, ga) + dot4(WI31, gb);
      float a4_ = dot4(WI40, ga) + dot4(WI41, gb);
      float a5 = dot4(WI50, ga) + dot4(WI51, gb);
      a0 = wred(a0); a1 = wred(a1); a2 = wred(a2);
      a3 = wred(a3); a4_ = wred(a4_); a5 = wred(a5);
      if (lane == 0) {
        float ir0 = a0 + BI0, iz0 = a1 + BI1, in0 = a2 + BI2;
        float rg0 = 1.f / (1.f + expf(-(ir0 + ghr0)));
        float zg0 = 1.f / (1.f + expf(-(iz0 + ghz0)));
        float ng0 = tanhf(in0 + rg0 * ghn0);
        float hp0 = ld1c(ws + OFF_HS + s * HDIM + r0);
        gstore(ws + OFF_HS + (s + 1) * HDIM + r0, (1.f - zg0) * ng0 + zg0 * hp0);
        float ir1 = a3 + BI3, iz1 = a4_ + BI4, in1 = a5 + BI5;
        float rg1 = 1.f / (1.f + expf(-(ir1 + ghr1)));
        float zg1 = 1.f / (1.f + expf(-(iz1 + ghz1)));
        float ng1 = tanhf(in1 + rg1 * ghn1);
        float hp1 = ld1c(ws + OFF_HS + s * HDIM + r1);
        gstore(ws + OFF_HS + (s + 1) * HDIM + r1, (1.f - zg1) * ng1 + zg1 * hp1);
      }
    }
    gbar(ws, bar++);
  }
}

// logits GEMM v9: s-partitioned waves. 256 threads (4 waves), 256 rows/block,
// 197 blocks (same chassis as proven k_final2). Wave w owns s-range
// [5w, min(5w+5,19)) and ALL 256 rows (4 rows/lane: lane+64j). Per chunk per
// wave: 8kq x (4 w-reads + <=5 h-reads) = <=72 LDS instrs vs k_final2's 160 —
// 2.2x less LDS issue, same staging/grid/LDS/occupancy. No cross-wave
// reduction (disjoint s). w-reads lane-contiguous (conflict-free WL layout);
// h-reads broadcast; outputs coalesced per (s, row-group).
#define WL(row, q) ((q) * 1032 + 4 * (row))
__global__ void __launch_bounds__(256) k_final9(const float* __restrict__ ow,
                                                const float* __restrict__ ob,
                                                const float* __restrict__ ws,
                                                float* __restrict__ out) {
  __shared__ __align__(16) float wl[8 * 1032];
  __shared__ __align__(16) float hl[T_STEPS * 512];
  int tid = threadIdx.x;
  int wave = tid >> 6, lane = tid & 63;
  int sbase = wave * 5;
  int scnt = (wave == 3) ? 4 : 5;
  long rbase = (long)blockIdx.x * 256;
  // stage h[1..19] (float4 vectorized)
  for (int j = tid; j < T_STEPS * 128; j += 256)
    *(float4*)&hl[4 * j] = *(const float4*)(ws + OFF_HS + 512 + 4 * j);
  float4 st[8];
#pragma unroll
  for (int i = 0; i < 8; ++i) {
    int f = tid + 256 * i; int row = f >> 3, q = f & 7;
    long r = rbase + row;
    st[i] = (r < V) ? *(const float4*)(ow + r * 512 + 4 * q) : make_float4(0.f, 0.f, 0.f, 0.f);
  }
  float acc[5][4];
#pragma unroll
  for (int sl = 0; sl < 5; ++sl)
#pragma unroll
    for (int j = 0; j < 4; ++j) acc[sl][j] = 0.f;
  __syncthreads();  // hl ready
  for (int c = 0; c < 16; ++c) {
#pragma unroll
    for (int i = 0; i < 8; ++i) {
      int f = tid + 256 * i; int row = f >> 3, q = f & 7;
      *(float4*)(&wl[WL(row, q)]) = st[i];
    }
    __syncthreads();  // wl ready
    if (c < 15) {
#pragma unroll
      for (int i = 0; i < 8; ++i) {
        int f = tid + 256 * i; int row = f >> 3, q = f & 7;
        long r = rbase + row;
        st[i] = (r < V) ? *(const float4*)(ow + r * 512 + (c + 1) * 32 + 4 * q) : make_float4(0.f, 0.f, 0.f, 0.f);
      }
    }
    // compute: wave owns s in [sbase, sbase+scnt), rows lane+64j for j=0..3
#pragma unroll
    for (int kq = 0; kq < 8; ++kq) {
      float4 w0 = *(const float4*)(&wl[WL(lane, kq)]);
      float4 w1 = *(const float4*)(&wl[WL(lane + 64, kq)]);
      float4 w2 = *(const float4*)(&wl[WL(lane + 128, kq)]);
      float4 w3 = *(const float4*)(&wl[WL(lane + 192, kq)]);
      const float* hb = hl + c * 32 + 4 * kq + sbase * 512;
#pragma unroll
      for (int sl = 0; sl < 5; ++sl) {
        if (sl < scnt) {
          float4 h4 = *(const float4*)(hb + sl * 512);
          acc[sl][0] += dot4(w0, h4);
          acc[sl][1] += dot4(w1, h4);
          acc[sl][2] += dot4(w2, h4);
          acc[sl][3] += dot4(w3, h4);
        }
      }
    }
    __syncthreads();  // done reading wl
  }
  // write: 4 coalesced rows per s
#pragma unroll
  for (int sl = 0; sl < 5; ++sl) {
    if (sl < scnt) {
      int s = sbase + sl;
#pragma unroll
      for (int j = 0; j < 4; ++j) {
        long r = rbase + 64 * j + lane;
        if (r < V) out[OUT_LOGITS + (long)s * V + r] = acc[sl][j] + ob[r];
      }
    }
  }
}

extern "C" void kernel_launch(void* const* d_in, const int* in_sizes, int n_in,
                              void* d_out, int out_size, void* d_ws, size_t ws_size,
                              hipStream_t stream) {
  const int*   input_tok  = (const int*)d_in[0];
  const float* hidden     = (const float*)d_in[1];
  const float* enc        = (const float*)d_in[2];
  const float* prop       = (const float*)d_in[3];
  const int*   obj_mask   = (const int*)d_in[4];
  const int*   lang_mask  = (const int*)d_in[5];
  const int*   ans        = (const int*)d_in[6];
  const float* emb        = (const float*)d_in[7];
  const float* attn_w1    = (const float*)d_in[8];
  const float* attn_b1    = (const float*)d_in[9];
  const float* attn_w2    = (const float*)d_in[10];
  const float* attn_b2    = (const float*)d_in[11];
  const float* attn_op_w1 = (const float*)d_in[12];
  const float* attn_op_b1 = (const float*)d_in[13];
  const float* attn_op_w2 = (const float*)d_in[14];
  const float* attn_op_b2 = (const float*)d_in[15];
  const float* cmb_w1     = (const float*)d_in[16];
  const float* cmb_b1     = (const float*)d_in[17];
  const float* cmb_w2     = (const float*)d_in[18];
  const float* cmb_b2     = (const float*)d_in[19];
  const float* gw_ih      = (const float*)d_in[20];
  const float* gw_hh      = (const float*)d_in[21];
  const float* gb_ih      = (const float*)d_in[22];
  const float* gb_hh      = (const float*)d_in[23];
  const float* out_w      = (const float*)d_in[24];
  const float* out_b      = (const float*)d_in[25];
  float* out = (float*)d_out;
  float* ws  = (float*)d_ws;

  // reset the 64 barrier flags (64B stride; monotonic; first barrier index is 1)
  hipMemsetAsync((char*)d_ws + (size_t)OFF_BAR * 4, 0, 4608, stream);
  k_pre1<<<25, 256, 0, stream>>>(input_tok, ans, emb, hidden, ws);
  k_pre2<<<4864, 256, 0, stream>>>(attn_op_w1, attn_op_b1, attn_w1, attn_b1, cmb_w1, cmb_b1, ws);
  k_mprep<<<512, 256, 0, stream>>>(cmb_w1, prop, enc, ws);
  k_recur<<<NBLK, 256, 0, stream>>>(attn_op_w1, attn_w1, gw_hh, gb_hh,
                                    attn_op_w2, attn_op_b2, attn_w2, attn_b2,
                                    obj_mask, lang_mask, cmb_w2, cmb_b2,
                                    gw_ih, gb_ih, ws, out);
  k_final9<<<(V + 255) / 256, 256, 0, stream>>>(out_w, out_b, ws, out);
}